// Round 5
// baseline (19834.692 us; speedup 1.0000x reference)
//
#include <hip/hip_runtime.h>
#include <hip/hip_bf16.h>
#include <stdint.h>
#include <math.h>

// Problem dims
constexpr int SEQ  = 4096;
constexpr int DIN  = 1152;
constexpr int HID  = 512;
constexpr int G4H  = 2048;   // 4*HID
constexpr int KTAG = 24;
constexpr float NEGV = -10000.0f;

__device__ __forceinline__ float sigm(float x) { return 1.0f / (1.0f + expf(-x)); }

// =====================================================================
// GEMM: C[SEQ][2048] = A[SEQ][KA] @ W[2048][KA]^T + b     (fp32, 64x64 tile)
// mode 0: A is a plain [SEQ][KA] matrix.
// mode 1: A row t is concat(hf[t+1][0:512], hb[SEQ-t][0:512])  (bidir LSTM output)
// blockIdx.z selects the (Wf,bf,Cf) or (Wb,bb,Cb) problem.
// =====================================================================
__global__ __launch_bounds__(256) void gemm_proj(
    const float* __restrict__ A, const float* __restrict__ hf, const float* __restrict__ hb,
    int KA, int mode,
    const float* __restrict__ Wf, const float* __restrict__ bf, float* __restrict__ Cf,
    const float* __restrict__ Wb, const float* __restrict__ bb, float* __restrict__ Cb)
{
    const float* W    = blockIdx.z ? Wb : Wf;
    const float* bias = blockIdx.z ? bb : bf;
    float*       C    = blockIdx.z ? Cb : Cf;

    __shared__ __align__(16) float As[32][68];   // [k][m], pad 68 to break conflicts, keep 16B align
    __shared__ __align__(16) float Ws[32][68];   // [k][n]

    const int tid  = threadIdx.x;
    const int bm   = blockIdx.x * 64;
    const int bn   = blockIdx.y * 64;
    const int lrow = tid >> 2;          // 0..63
    const int kq   = (tid & 3) * 8;     // 0,8,16,24
    const int tx   = tid & 15, ty = tid >> 4;

    float acc[4][4] = {};

    for (int bk = 0; bk < KA; bk += 32) {
        float4 a0, a1;
        const int arow = bm + lrow;
        const int k0   = bk + kq;
        if (mode == 0) {
            const float* p = A + (size_t)arow * KA + k0;
            a0 = *(const float4*)p;
            a1 = *(const float4*)(p + 4);
        } else {
            const float* p0 = (k0 < 512) ? (hf + (size_t)(arow + 1) * HID + k0)
                                         : (hb + (size_t)(SEQ - arow) * HID + (k0 - 512));
            const int k1 = k0 + 4;
            const float* p1 = (k1 < 512) ? (hf + (size_t)(arow + 1) * HID + k1)
                                         : (hb + (size_t)(SEQ - arow) * HID + (k1 - 512));
            a0 = *(const float4*)p0;
            a1 = *(const float4*)p1;
        }
        const float* q = W + (size_t)(bn + lrow) * KA + k0;
        const float4 w0 = *(const float4*)q;
        const float4 w1 = *(const float4*)(q + 4);

        As[kq+0][lrow] = a0.x; As[kq+1][lrow] = a0.y; As[kq+2][lrow] = a0.z; As[kq+3][lrow] = a0.w;
        As[kq+4][lrow] = a1.x; As[kq+5][lrow] = a1.y; As[kq+6][lrow] = a1.z; As[kq+7][lrow] = a1.w;
        Ws[kq+0][lrow] = w0.x; Ws[kq+1][lrow] = w0.y; Ws[kq+2][lrow] = w0.z; Ws[kq+3][lrow] = w0.w;
        Ws[kq+4][lrow] = w1.x; Ws[kq+5][lrow] = w1.y; Ws[kq+6][lrow] = w1.z; Ws[kq+7][lrow] = w1.w;
        __syncthreads();

        #pragma unroll
        for (int kk = 0; kk < 32; ++kk) {
            const float4 av = *(const float4*)&As[kk][ty * 4];
            const float4 wv = *(const float4*)&Ws[kk][tx * 4];
            acc[0][0] = fmaf(av.x, wv.x, acc[0][0]); acc[0][1] = fmaf(av.x, wv.y, acc[0][1]);
            acc[0][2] = fmaf(av.x, wv.z, acc[0][2]); acc[0][3] = fmaf(av.x, wv.w, acc[0][3]);
            acc[1][0] = fmaf(av.y, wv.x, acc[1][0]); acc[1][1] = fmaf(av.y, wv.y, acc[1][1]);
            acc[1][2] = fmaf(av.y, wv.z, acc[1][2]); acc[1][3] = fmaf(av.y, wv.w, acc[1][3]);
            acc[2][0] = fmaf(av.z, wv.x, acc[2][0]); acc[2][1] = fmaf(av.z, wv.y, acc[2][1]);
            acc[2][2] = fmaf(av.z, wv.z, acc[2][2]); acc[2][3] = fmaf(av.z, wv.w, acc[2][3]);
            acc[3][0] = fmaf(av.w, wv.x, acc[3][0]); acc[3][1] = fmaf(av.w, wv.y, acc[3][1]);
            acc[3][2] = fmaf(av.w, wv.z, acc[3][2]); acc[3][3] = fmaf(av.w, wv.w, acc[3][3]);
        }
        __syncthreads();
    }

    const float4 bv = *(const float4*)&bias[bn + tx * 4];
    #pragma unroll
    for (int im = 0; im < 4; ++im) {
        float4 o;
        o.x = acc[im][0] + bv.x; o.y = acc[im][1] + bv.y;
        o.z = acc[im][2] + bv.z; o.w = acc[im][3] + bv.w;
        *(float4*)&C[(size_t)(bm + ty * 4 + im) * G4H + bn + tx * 4] = o;
    }
}

// =====================================================================
// Persistent bidirectional LSTM layer, v5 (resubmit after infra failure).
// Structure = v4 (64 WGs x 512 thr, 16 units/WG, wave-local combine,
// single 64B hist store) with three latency-chain changes:
//   1. Whh weights PINNED in VGPRs via empty asm "+v" keep-alives.
//      v4 compiled to 56 VGPR -> the 16x dwordx4 weight loads were
//      re-issued from L2 every step inside the serial matvec phase.
//      2 waves/SIMD permits 256 VGPR, so residency is free.
//   2. 2-deep software-pipelined sentinel poll: one load in flight
//      while checking the previous -> expected catch drops by ~L/2
//      since poll issue period no longer equals the LLC load latency.
//   3. Polling moved to waves 1-4 (256 threads x uint64). Wave 0's
//      cell-update lanes run their ~300cy libm tail fully overlapped
//      with the polling instead of in series before it.
// All fp arithmetic identical to v4 (bit-exact, absmax must stay 0.0).
// h exchanged via hist[s] slots, NaN-sentinel value-spin (relaxed agent
// atomics); hist pre-filled 0xFF.
// Hang audit: poll targets are written by each WG's tid<16 lanes with no
// dependency on pollers (store precedes B2); all threads reach B1/B2
// unconditionally; uint64 loads 8B-aligned.
// =====================================================================
__global__ __launch_bounds__(512, 2) void lstm_layer(
    const float* __restrict__ Pf, const float* __restrict__ Pb,
    const float* __restrict__ Whhf, const float* __restrict__ Whhb,
    const float* __restrict__ h0, const float* __restrict__ c0, int h0base,
    float* __restrict__ histf, float* __restrict__ histb)
{
    const int wg  = blockIdx.x;
    const int dir = wg >> 5;            // 0 fwd, 1 bwd (32 WGs each)
    const int w   = wg & 31;            // slice id: units [w*16, w*16+16)
    const float* P    = dir ? Pb : Pf;
    const float* Whh  = dir ? Whhb : Whhf;
    float* histW      = dir ? histb : histf;

    const int tid  = threadIdx.x;              // 0..511
    const int wave = tid >> 6;                 // 0..7
    const int lane = tid & 63;
    const int q    = lane >> 3;                // k-chunk 0..7
    const int rr   = lane & 7;                 // row-in-wave 0..7
    const int g    = wave >> 1;                // gate 0..3 (i,f,g,o)
    const int usub = (wave & 1) * 8;
    const int uu   = usub + rr;                // unit-in-WG 0..15 (this row)
    const int unit = w * 16 + uu;              // global unit [0,512)
    const int grow = g * HID + unit;           // z-row [0,2048)

    // weights -> VGPR-resident registers (64 floats). The empty asm with
    // "+v" marks each component as modified -> the compiler cannot
    // rematerialize the loads inside the step loop (v4: VGPR=56 = reloads).
    const float4* wp = (const float4*)(Whh + (size_t)grow * HID + q * 64);
    float4 w0 = wp[0],  w1 = wp[1],  w2 = wp[2],  w3 = wp[3];
    float4 w4 = wp[4],  w5 = wp[5],  w6 = wp[6],  w7 = wp[7];
    float4 w8 = wp[8],  w9 = wp[9],  wA = wp[10], wB = wp[11];
    float4 wC = wp[12], wD = wp[13], wE = wp[14], wF = wp[15];
    asm volatile("" : "+v"(w0.x), "+v"(w0.y), "+v"(w0.z), "+v"(w0.w),
                      "+v"(w1.x), "+v"(w1.y), "+v"(w1.z), "+v"(w1.w),
                      "+v"(w2.x), "+v"(w2.y), "+v"(w2.z), "+v"(w2.w),
                      "+v"(w3.x), "+v"(w3.y), "+v"(w3.z), "+v"(w3.w));
    asm volatile("" : "+v"(w4.x), "+v"(w4.y), "+v"(w4.z), "+v"(w4.w),
                      "+v"(w5.x), "+v"(w5.y), "+v"(w5.z), "+v"(w5.w),
                      "+v"(w6.x), "+v"(w6.y), "+v"(w6.z), "+v"(w6.w),
                      "+v"(w7.x), "+v"(w7.y), "+v"(w7.z), "+v"(w7.w));
    asm volatile("" : "+v"(w8.x), "+v"(w8.y), "+v"(w8.z), "+v"(w8.w),
                      "+v"(w9.x), "+v"(w9.y), "+v"(w9.z), "+v"(w9.w),
                      "+v"(wA.x), "+v"(wA.y), "+v"(wA.z), "+v"(wA.w),
                      "+v"(wB.x), "+v"(wB.y), "+v"(wB.z), "+v"(wB.w));
    asm volatile("" : "+v"(wC.x), "+v"(wC.y), "+v"(wC.z), "+v"(wC.w),
                      "+v"(wD.x), "+v"(wD.y), "+v"(wD.z), "+v"(wD.w),
                      "+v"(wE.x), "+v"(wE.y), "+v"(wE.z), "+v"(wE.w),
                      "+v"(wF.x), "+v"(wF.y), "+v"(wF.z), "+v"(wF.w));

    // cell state on the first 16 threads (one per unit)
    float c = 0.0f;
    if (tid < 16) c = c0[(size_t)(h0base + dir) * HID + w * 16 + tid];

    // padded h: chunk k lives at [k*68, k*68+64); word (68k+4i) -> bank
    // 4(k+i)%32: the 8 chunk-groups of a wave hit 8 distinct banks per
    // ds_read_b128 (8-lane broadcast within each group) -> conflict-free.
    __shared__ __align__(16) float hsp[8 * 68];
    __shared__ float zb[4][16];

    // initial h into padded LDS
    hsp[(tid >> 6) * 68 + (tid & 63)] = h0[(size_t)(h0base + dir) * HID + tid];
    __syncthreads();

    // zP for step 0; thereafter software-pipelined one step ahead (q==0 lanes)
    float zPc = 0.0f;
    if (q == 0) zPc = P[(size_t)(dir ? (SEQ - 1) : 0) * G4H + grow];

    for (int s = 0; s < SEQ; ++s) {
        // prefetch NEXT step's input-projection term (off critical path)
        float zPn = 0.0f;
        if (q == 0 && s + 1 < SEQ) {
            const int tn = dir ? (SEQ - 2 - s) : (s + 1);
            zPn = P[(size_t)tn * G4H + grow];
        }

        // matvec partial: this lane's ordered 64-fma chain, k in [64q,64q+64)
        float acc = 0.0f;
        {
            const float* hb4 = &hsp[q * 68];
            float4 h4;
            h4 = *(const float4*)&hb4[ 0]; acc = fmaf(w0.x,h4.x,acc); acc = fmaf(w0.y,h4.y,acc); acc = fmaf(w0.z,h4.z,acc); acc = fmaf(w0.w,h4.w,acc);
            h4 = *(const float4*)&hb4[ 4]; acc = fmaf(w1.x,h4.x,acc); acc = fmaf(w1.y,h4.y,acc); acc = fmaf(w1.z,h4.z,acc); acc = fmaf(w1.w,h4.w,acc);
            h4 = *(const float4*)&hb4[ 8]; acc = fmaf(w2.x,h4.x,acc); acc = fmaf(w2.y,h4.y,acc); acc = fmaf(w2.z,h4.z,acc); acc = fmaf(w2.w,h4.w,acc);
            h4 = *(const float4*)&hb4[12]; acc = fmaf(w3.x,h4.x,acc); acc = fmaf(w3.y,h4.y,acc); acc = fmaf(w3.z,h4.z,acc); acc = fmaf(w3.w,h4.w,acc);
            h4 = *(const float4*)&hb4[16]; acc = fmaf(w4.x,h4.x,acc); acc = fmaf(w4.y,h4.y,acc); acc = fmaf(w4.z,h4.z,acc); acc = fmaf(w4.w,h4.w,acc);
            h4 = *(const float4*)&hb4[20]; acc = fmaf(w5.x,h4.x,acc); acc = fmaf(w5.y,h4.y,acc); acc = fmaf(w5.z,h4.z,acc); acc = fmaf(w5.w,h4.w,acc);
            h4 = *(const float4*)&hb4[24]; acc = fmaf(w6.x,h4.x,acc); acc = fmaf(w6.y,h4.y,acc); acc = fmaf(w6.z,h4.z,acc); acc = fmaf(w6.w,h4.w,acc);
            h4 = *(const float4*)&hb4[28]; acc = fmaf(w7.x,h4.x,acc); acc = fmaf(w7.y,h4.y,acc); acc = fmaf(w7.z,h4.z,acc); acc = fmaf(w7.w,h4.w,acc);
            h4 = *(const float4*)&hb4[32]; acc = fmaf(w8.x,h4.x,acc); acc = fmaf(w8.y,h4.y,acc); acc = fmaf(w8.z,h4.z,acc); acc = fmaf(w8.w,h4.w,acc);
            h4 = *(const float4*)&hb4[36]; acc = fmaf(w9.x,h4.x,acc); acc = fmaf(w9.y,h4.y,acc); acc = fmaf(w9.z,h4.z,acc); acc = fmaf(w9.w,h4.w,acc);
            h4 = *(const float4*)&hb4[40]; acc = fmaf(wA.x,h4.x,acc); acc = fmaf(wA.y,h4.y,acc); acc = fmaf(wA.z,h4.z,acc); acc = fmaf(wA.w,h4.w,acc);
            h4 = *(const float4*)&hb4[44]; acc = fmaf(wB.x,h4.x,acc); acc = fmaf(wB.y,h4.y,acc); acc = fmaf(wB.z,h4.z,acc); acc = fmaf(wB.w,h4.w,acc);
            h4 = *(const float4*)&hb4[48]; acc = fmaf(wC.x,h4.x,acc); acc = fmaf(wC.y,h4.y,acc); acc = fmaf(wC.z,h4.z,acc); acc = fmaf(wC.w,h4.w,acc);
            h4 = *(const float4*)&hb4[52]; acc = fmaf(wD.x,h4.x,acc); acc = fmaf(wD.y,h4.y,acc); acc = fmaf(wD.z,h4.z,acc); acc = fmaf(wD.w,h4.w,acc);
            h4 = *(const float4*)&hb4[56]; acc = fmaf(wE.x,h4.x,acc); acc = fmaf(wE.y,h4.y,acc); acc = fmaf(wE.z,h4.z,acc); acc = fmaf(wE.w,h4.w,acc);
            h4 = *(const float4*)&hb4[60]; acc = fmaf(wF.x,h4.x,acc); acc = fmaf(wF.y,h4.y,acc); acc = fmaf(wF.z,h4.z,acc); acc = fmaf(wF.w,h4.w,acc);
        }

        // s2_i = c_{2i} + c_{2i+1}: even-q lanes hold own(even) + partner(odd)
        const float s2 = acc + __shfl_xor(acc, 8);
        // z = ((s2_0 + s2_1) + s2_2) + s2_3 + zP   (exact v1 association);
        // s2_i is valid on lanes 16*i + rr (q = 2i, even).
        float z = __shfl(s2, rr) + __shfl(s2, 16 + rr);
        z += __shfl(s2, 32 + rr);
        z += __shfl(s2, 48 + rr);
        z += __shfl(zPc, rr);                      // zP lives on q==0 lane rr of this wave

        // write this row's z once (q==0 lanes), gate combine via LDS
        if (q == 0) zb[g][uu] = z;
        __syncthreads();                           // B1: zb ready, hsp reads done

        if (tid < 16) {
            const float zi = zb[0][tid];
            const float zf = zb[1][tid];
            const float zg = zb[2][tid];
            const float zo = zb[3][tid];
            const float cn = sigm(zf) * c + sigm(zi) * tanhf(zg);
            const float hv = sigm(zo) * tanhf(cn);
            c = cn;
            // 16 lanes x 4B contiguous, 64B-aligned = one write transaction
            __hip_atomic_store(&histW[(size_t)(s + 1) * HID + w * 16 + tid], hv,
                               __ATOMIC_RELAXED, __HIP_MEMORY_SCOPE_AGENT);
        }
        zPc = zPn;

        if (s + 1 < SEQ) {
            // Pollers are waves 1-4 (256 threads x uint64 = all 512 words):
            // wave 0's cell tail overlaps the poll instead of preceding it.
            // 2-deep pipelined poll: one load in flight while checking the
            // previous (values are write-once: any non-sentinel read is final).
            if (tid >= 64 && tid < 320) {
                const int idx = tid - 64;          // word-pair 0..255
                const uint64_t* src = (const uint64_t*)(histW + (size_t)(s + 1) * HID);
                uint64_t A = __hip_atomic_load(&src[idx], __ATOMIC_RELAXED, __HIP_MEMORY_SCOPE_AGENT);
                uint64_t B = __hip_atomic_load(&src[idx], __ATOMIC_RELAXED, __HIP_MEMORY_SCOPE_AGENT);
                while ((uint32_t)A == 0xFFFFFFFFu || (uint32_t)(A >> 32) == 0xFFFFFFFFu) {
                    A = B;
                    B = __hip_atomic_load(&src[idx], __ATOMIC_RELAXED, __HIP_MEMORY_SCOPE_AGENT);
                }
                const int e = idx * 2;
                float2 h2;
                h2.x = __uint_as_float((uint32_t)A);
                h2.y = __uint_as_float((uint32_t)(A >> 32));
                *(float2*)&hsp[(e >> 6) * 68 + (e & 63)] = h2;
            }
            __syncthreads();                       // B2: hs[s+1] complete
        }
    }
}

// =====================================================================
// feats[t][j] = b_tag[j] + sum_k y1[t][k] * Wtag[j][k], y1 from hist buffers.
// One wave per t-row.
// =====================================================================
__global__ __launch_bounds__(256) void feats_kernel(
    const float* __restrict__ hf, const float* __restrict__ hb,
    const float* __restrict__ Wtag, const float* __restrict__ btag, float* __restrict__ feats)
{
    const int wv = threadIdx.x >> 6, lane = threadIdx.x & 63;
    const int t  = blockIdx.x * 4 + wv;
    const int k0 = lane * 16;
    const float* src = (k0 < 512) ? (hf + (size_t)(t + 1) * HID + k0)
                                  : (hb + (size_t)(SEQ - t) * HID + (k0 - 512));
    const float4 y0 = ((const float4*)src)[0];
    const float4 y1 = ((const float4*)src)[1];
    const float4 y2 = ((const float4*)src)[2];
    const float4 y3 = ((const float4*)src)[3];
    for (int j = 0; j < KTAG; ++j) {
        const float4* wp = (const float4*)&Wtag[(size_t)j * 1024 + k0];
        const float4 w0 = wp[0], w1 = wp[1], w2 = wp[2], w3 = wp[3];
        float p = 0.0f;
        p = fmaf(y0.x, w0.x, p); p = fmaf(y0.y, w0.y, p); p = fmaf(y0.z, w0.z, p); p = fmaf(y0.w, w0.w, p);
        p = fmaf(y1.x, w1.x, p); p = fmaf(y1.y, w1.y, p); p = fmaf(y1.z, w1.z, p); p = fmaf(y1.w, w1.w, p);
        p = fmaf(y2.x, w2.x, p); p = fmaf(y2.y, w2.y, p); p = fmaf(y2.z, w2.z, p); p = fmaf(y2.w, w2.w, p);
        p = fmaf(y3.x, w3.x, p); p = fmaf(y3.y, w3.y, p); p = fmaf(y3.z, w3.z, p); p = fmaf(y3.w, w3.w, p);
        #pragma unroll
        for (int off = 32; off; off >>= 1) p += __shfl_xor(p, off);
        if (lane == 0) feats[(size_t)t * KTAG + j] = p + btag[j];
    }
}

// =====================================================================
// Sequential Viterbi max scan (bit-exact vs reference, no argmax on chain).
// 1 wave. Lane layout: to = lane%24, half = lane/24 covers 12 'from' each.
// fv rows stored to fvstore (slot 0 = init, slot t+1 = fv_t) for bp recompute.
// =====================================================================
__global__ __launch_bounds__(64) void viterbi_scan(
    const float* __restrict__ feats, const float* __restrict__ trans,
    float* __restrict__ fvstore, float* __restrict__ out, int* __restrict__ bestb)
{
    const int lane = threadIdx.x;
    const int to = lane % 24, hh = lane / 24;
    const bool act = hh < 2;
    const int hb = (hh & 1) * 12;

    float tr[12], fvr[12];
    #pragma unroll
    for (int i = 0; i < 12; ++i) tr[i] = act ? trans[to * 24 + hb + i] : -3.0e37f;
    #pragma unroll
    for (int i = 0; i < 12; ++i) fvr[i] = (hb + i == 0) ? 0.0f : NEGV;
    if (lane < 24) fvstore[lane] = (lane == 0) ? 0.0f : NEGV;

    float ftc = (lane < 24) ? feats[lane] : 0.0f;
    const int partner = act ? (to + ((hh ^ 1) * 24)) : lane;
    float fvnew = 0.0f;

    for (int t = 0; t < SEQ; ++t) {
        const float ftn = (lane < 24 && t + 1 < SEQ) ? feats[(size_t)(t + 1) * KTAG + lane] : 0.0f;
        float v0  = fvr[0]  + tr[0],  v1  = fvr[1]  + tr[1];
        float v2  = fvr[2]  + tr[2],  v3  = fvr[3]  + tr[3];
        float v4  = fvr[4]  + tr[4],  v5  = fvr[5]  + tr[5];
        float v6  = fvr[6]  + tr[6],  v7  = fvr[7]  + tr[7];
        float v8  = fvr[8]  + tr[8],  v9  = fvr[9]  + tr[9];
        float v10 = fvr[10] + tr[10], v11 = fvr[11] + tr[11];
        float m = fmaxf(fmaxf(fmaxf(v0, v1), fmaxf(v2, v3)),
                        fmaxf(fmaxf(v4, v5), fmaxf(v6, v7)));
        m = fmaxf(m, fmaxf(fmaxf(v8, v9), fmaxf(v10, v11)));
        m = fmaxf(m, __shfl(m, partner));
        fvnew = m + ftc;                 // valid on lanes < 24
        if (lane < 24) fvstore[(size_t)(t + 1) * KTAG + lane] = fvnew;
        #pragma unroll
        for (int i = 0; i < 12; ++i) fvr[i] = __shfl(fvnew, hb + i);   // re-replicate
        ftc = ftn;
    }

    // terminal
    float val = -3.0e38f; int idx = lane;
    if (lane < 24) {
        val = fvnew + trans[1 * 24 + lane];          // transitions[STOP][from]
        if (lane == 0 || lane == 1) val = NEGV;      // exclude START, STOP
    }
    #pragma unroll
    for (int off = 16; off; off >>= 1) {
        const float ov = __shfl_xor(val, off);
        const int   oi = __shfl_xor(idx, off);
        if (ov > val || (ov == val && oi < idx)) { val = ov; idx = oi; }
    }
    if (lane == 0) { out[0] = val; *bestb = idx; }
}

// =====================================================================
// Recompute backpointers in parallel: bp[t][to] = argmax_from(fv_{t-1}[from]+trans)
// Identical fp32 adds + first-index tie rule -> matches the sequential scan.
// =====================================================================
__global__ __launch_bounds__(256) void bp_kernel(
    const float* __restrict__ fvstore, const float* __restrict__ trans, uint8_t* __restrict__ bp)
{
    const int idx = blockIdx.x * 256 + threadIdx.x;
    const int t = idx / KTAG, to = idx % KTAG;
    const float* fv = fvstore + (size_t)t * KTAG;   // slot t = fv_{t-1}
    const float* tr = trans + to * 24;
    float m = fv[0] + tr[0]; int bi = 0;
    #pragma unroll
    for (int f = 1; f < 24; ++f) {
        const float v = fv[f] + tr[f];
        if (v > m) { m = v; bi = f; }
    }
    bp[idx] = (uint8_t)bi;
}

// =====================================================================
// Parallel backtrace via exact integer map composition over 64-step chunks.
// =====================================================================
__global__ __launch_bounds__(1024) void backtrace_kernel(
    const uint8_t* __restrict__ bp, const int* __restrict__ bestb, float* __restrict__ out)
{
    __shared__ uint8_t E[64][24];
    __shared__ uint8_t tops[64];
    const int tid = threadIdx.x;
    const int wv = tid >> 6, lane = tid & 63;

    // phase 1: chunk maps E_c: top_c -> top_{c-1} (applies bp[64c+63] .. bp[64c])
    for (int ci = 0; ci < 4; ++ci) {
        const int ck = wv * 4 + ci;
        if (lane < 24) {
            int y = lane;
            for (int k = 63; k >= 0; --k) y = bp[(size_t)(ck * 64 + k) * KTAG + y];
            E[ck][lane] = (uint8_t)y;
        }
    }
    __syncthreads();

    // phase 2: serial fold over 64 chunk maps
    if (tid == 0) {
        int topc = *bestb;
        tops[63] = (uint8_t)topc;
        for (int ck = 63; ck >= 1; --ck) { topc = E[ck][topc]; tops[ck - 1] = (uint8_t)topc; }
    }
    __syncthreads();

    // phase 3: fill each chunk
    for (int ci = 0; ci < 4; ++ci) {
        const int ck = wv * 4 + ci;
        if (lane == 0) {
            int y = tops[ck];
            out[1 + ck * 64 + 63] = (float)y;
            for (int tt = ck * 64 + 62; tt >= ck * 64; --tt) {
                y = bp[(size_t)(tt + 1) * KTAG + y];
                out[1 + tt] = (float)y;
            }
        }
    }
}

// =====================================================================
extern "C" void kernel_launch(void* const* d_in, const int* in_sizes, int n_in,
                              void* d_out, int out_size, void* d_ws, size_t ws_size,
                              hipStream_t stream)
{
    (void)in_sizes; (void)n_in; (void)out_size; (void)ws_size;
    // Inputs in setup_inputs() dict INSERTION order: transitions is added
    // LAST (after h0/c0), even though the reference signature lists it earlier.
    const float* X     = (const float*)d_in[0];
    const float* Wih0f = (const float*)d_in[1];
    const float* Whh0f = (const float*)d_in[2];
    const float* b0f   = (const float*)d_in[3];
    const float* Wih0b = (const float*)d_in[4];
    const float* Whh0b = (const float*)d_in[5];
    const float* b0b   = (const float*)d_in[6];
    const float* Wih1f = (const float*)d_in[7];
    const float* Whh1f = (const float*)d_in[8];
    const float* b1f   = (const float*)d_in[9];
    const float* Wih1b = (const float*)d_in[10];
    const float* Whh1b = (const float*)d_in[11];
    const float* b1b   = (const float*)d_in[12];
    const float* Wtag  = (const float*)d_in[13];
    const float* btag  = (const float*)d_in[14];
    const float* h0    = (const float*)d_in[15];
    const float* c0    = (const float*)d_in[16];
    const float* trans = (const float*)d_in[17];
    float* out = (float*)d_out;

    // workspace carve-up (floats)
    float* f   = (float*)d_ws;
    float* Pf  = f;                                   // SEQ*2048
    float* Pb  = Pf  + (size_t)SEQ * G4H;             // SEQ*2048
    float* hf0 = Pb  + (size_t)SEQ * G4H;             // (SEQ+1)*512 each
    float* hb0 = hf0 + (size_t)(SEQ + 1) * HID;
    float* hf1 = hb0 + (size_t)(SEQ + 1) * HID;
    float* hb1 = hf1 + (size_t)(SEQ + 1) * HID;
    float* feats = hb1 + (size_t)(SEQ + 1) * HID;     // SEQ*24
    float* fvst  = feats + (size_t)SEQ * KTAG;        // (SEQ+1)*24
    int*   bestb = (int*)(fvst + (size_t)(SEQ + 1) * KTAG);
    uint8_t* bp  = (uint8_t*)(bestb + 4);             // SEQ*24 bytes

    // NaN-sentinel fill for all 4 hist buffers (sync mechanism for the LSTM)
    hipMemsetAsync(hf0, 0xFF, (size_t)4 * (SEQ + 1) * HID * sizeof(float), stream);

    // layer 0: input projection, then persistent bidirectional recurrence
    gemm_proj<<<dim3(SEQ / 64, G4H / 64, 2), 256, 0, stream>>>(
        X, nullptr, nullptr, DIN, 0, Wih0f, b0f, Pf, Wih0b, b0b, Pb);
    lstm_layer<<<64, 512, 0, stream>>>(Pf, Pb, Whh0f, Whh0b, h0, c0, 0, hf0, hb0);

    // layer 1 (P buffers reused; layer-0 input y0 read straight from hist)
    gemm_proj<<<dim3(SEQ / 64, G4H / 64, 2), 256, 0, stream>>>(
        nullptr, hf0, hb0, 1024, 1, Wih1f, b1f, Pf, Wih1b, b1b, Pb);
    lstm_layer<<<64, 512, 0, stream>>>(Pf, Pb, Whh1f, Whh1b, h0, c0, 2, hf1, hb1);

    // tag head + Viterbi
    feats_kernel<<<SEQ / 4, 256, 0, stream>>>(hf1, hb1, Wtag, btag, feats);
    viterbi_scan<<<1, 64, 0, stream>>>(feats, trans, fvst, out, bestb);
    bp_kernel<<<(SEQ * KTAG) / 256, 256, 0, stream>>>(fvst, trans, bp);
    backtrace_kernel<<<1, 1024, 0, stream>>>(bp, bestb, out);
}

// Round 6
// 17450.583 us; speedup vs baseline: 1.1366x; 1.1366x over previous
//
#include <hip/hip_runtime.h>
#include <hip/hip_bf16.h>
#include <stdint.h>
#include <math.h>

// Problem dims
constexpr int SEQ  = 4096;
constexpr int DIN  = 1152;
constexpr int HID  = 512;
constexpr int G4H  = 2048;   // 4*HID
constexpr int KTAG = 24;
constexpr float NEGV = -10000.0f;

__device__ __forceinline__ float sigm(float x) { return 1.0f / (1.0f + expf(-x)); }

// =====================================================================
// GEMM: C[SEQ][2048] = A[SEQ][KA] @ W[2048][KA]^T + b   (fp32, 128x128 tile,
// 8x8 per thread, K-step 16). Per-element accumulation is a single fmaf
// chain in strictly ascending k with bias added last -> BIT-EXACT with the
// previous 64x64 tiling (absmax must stay 0.0).
// mode 0: A is a plain [SEQ][KA] matrix.
// mode 1: A row t is concat(hf[t+1][0:512], hb[SEQ-t][0:512]).
// blockIdx.z selects the (Wf,bf,Cf) or (Wb,bb,Cb) problem.
// Ws uses a bank-spread layout pos(j)=j+4*(j>>5) so the 16-address,
// 8-float-stride bv read pattern is 2-way (free) instead of 4-way.
// =====================================================================
__global__ __launch_bounds__(256) void gemm_proj(
    const float* __restrict__ A, const float* __restrict__ hf, const float* __restrict__ hb,
    int KA, int mode,
    const float* __restrict__ Wf, const float* __restrict__ bf, float* __restrict__ Cf,
    const float* __restrict__ Wb, const float* __restrict__ bb, float* __restrict__ Cb)
{
    const float* W    = blockIdx.z ? Wb : Wf;
    const float* bias = blockIdx.z ? bb : bf;
    float*       C    = blockIdx.z ? Cb : Cf;

    __shared__ __align__(16) float As[16][132];   // [k][m], pad 132
    __shared__ __align__(16) float Ws[16][144];   // [k][pos(n)], bank-spread

    const int tid  = threadIdx.x;
    const int bm   = blockIdx.x * 128;
    const int bn   = blockIdx.y * 128;
    const int lrow = tid >> 1;            // 0..127
    const int kq   = (tid & 1) * 8;       // 0 or 8
    const int tx   = tid & 15;            // col block (8 wide)
    const int ty   = tid >> 4;            // row block (8 tall)
    const int wpos = lrow + 4 * (lrow >> 5);        // Ws write position
    const int bpos = tx * 8 + 4 * (tx >> 2);        // Ws read position (= pos(tx*8))

    float acc[8][8] = {};

    for (int bk = 0; bk < KA; bk += 16) {
        float4 a0, a1;
        const int arow = bm + lrow;
        const int k0   = bk + kq;
        if (mode == 0) {
            const float* p = A + (size_t)arow * KA + k0;
            a0 = *(const float4*)p;
            a1 = *(const float4*)(p + 4);
        } else {
            const float* p0 = (k0 < 512) ? (hf + (size_t)(arow + 1) * HID + k0)
                                         : (hb + (size_t)(SEQ - arow) * HID + (k0 - 512));
            const int k1 = k0 + 4;
            const float* p1 = (k1 < 512) ? (hf + (size_t)(arow + 1) * HID + k1)
                                         : (hb + (size_t)(SEQ - arow) * HID + (k1 - 512));
            a0 = *(const float4*)p0;
            a1 = *(const float4*)p1;
        }
        const float* qp = W + (size_t)(bn + lrow) * KA + k0;
        const float4 w0 = *(const float4*)qp;
        const float4 w1 = *(const float4*)(qp + 4);

        As[kq+0][lrow] = a0.x; As[kq+1][lrow] = a0.y; As[kq+2][lrow] = a0.z; As[kq+3][lrow] = a0.w;
        As[kq+4][lrow] = a1.x; As[kq+5][lrow] = a1.y; As[kq+6][lrow] = a1.z; As[kq+7][lrow] = a1.w;
        Ws[kq+0][wpos] = w0.x; Ws[kq+1][wpos] = w0.y; Ws[kq+2][wpos] = w0.z; Ws[kq+3][wpos] = w0.w;
        Ws[kq+4][wpos] = w1.x; Ws[kq+5][wpos] = w1.y; Ws[kq+6][wpos] = w1.z; Ws[kq+7][wpos] = w1.w;
        __syncthreads();

        #pragma unroll
        for (int kk = 0; kk < 16; ++kk) {
            const float4 av0 = *(const float4*)&As[kk][ty * 8];
            const float4 av1 = *(const float4*)&As[kk][ty * 8 + 4];
            const float4 bv0 = *(const float4*)&Ws[kk][bpos];
            const float4 bv1 = *(const float4*)&Ws[kk][bpos + 4];
            const float a8[8] = {av0.x, av0.y, av0.z, av0.w, av1.x, av1.y, av1.z, av1.w};
            const float b8[8] = {bv0.x, bv0.y, bv0.z, bv0.w, bv1.x, bv1.y, bv1.z, bv1.w};
            #pragma unroll
            for (int i = 0; i < 8; ++i)
                #pragma unroll
                for (int j = 0; j < 8; ++j)
                    acc[i][j] = fmaf(a8[i], b8[j], acc[i][j]);
        }
        __syncthreads();
    }

    const float4 bx0 = *(const float4*)&bias[bn + tx * 8];
    const float4 bx1 = *(const float4*)&bias[bn + tx * 8 + 4];
    #pragma unroll
    for (int im = 0; im < 8; ++im) {
        float4 o0, o1;
        o0.x = acc[im][0] + bx0.x; o0.y = acc[im][1] + bx0.y;
        o0.z = acc[im][2] + bx0.z; o0.w = acc[im][3] + bx0.w;
        o1.x = acc[im][4] + bx1.x; o1.y = acc[im][5] + bx1.y;
        o1.z = acc[im][6] + bx1.z; o1.w = acc[im][7] + bx1.w;
        float* cp = &C[(size_t)(bm + ty * 8 + im) * G4H + bn + tx * 8];
        *(float4*)cp = o0;
        *(float4*)(cp + 4) = o1;
    }
}

// =====================================================================
// Persistent bidirectional LSTM layer, v6 = v4 base (64 WGs x 512 thr,
// 16 units/WG, wave-local combine, single 64B hist store; NO asm weight
// pin — v5 proved it forces a scratch spill: VGPR stayed 52, lstm
// 7475->8856us) with two latency-chain changes:
//   1. PRE-BARRIER gate activations: sigm/tanh are unary, so the waves
//      that computed z apply them before B1 (wave-uniform g==2 branch).
//      Post-B1 tail shrinks from {LDS read + 4 transcendental chains}
//      to {LDS read + 1 fma + 1 tanhf + store}. Bit-exact.
//   2. 2-deep software-pipelined sentinel poll (v4's all-512-thread
//      uint32 scheme, one extra load in flight): poll catch alignment
//      drops ~L/2 since issue period no longer equals LLC load latency.
// h exchanged via hist[s] slots, NaN-sentinel value-spin (relaxed agent
// atomics); hist pre-filled 0xFF.
// =====================================================================
__global__ __launch_bounds__(512, 2) void lstm_layer(
    const float* __restrict__ Pf, const float* __restrict__ Pb,
    const float* __restrict__ Whhf, const float* __restrict__ Whhb,
    const float* __restrict__ h0, const float* __restrict__ c0, int h0base,
    float* __restrict__ histf, float* __restrict__ histb)
{
    const int wg  = blockIdx.x;
    const int dir = wg >> 5;            // 0 fwd, 1 bwd (32 WGs each)
    const int w   = wg & 31;            // slice id: units [w*16, w*16+16)
    const float* P    = dir ? Pb : Pf;
    const float* Whh  = dir ? Whhb : Whhf;
    float* histW      = dir ? histb : histf;

    const int tid  = threadIdx.x;              // 0..511
    const int wave = tid >> 6;                 // 0..7
    const int lane = tid & 63;
    const int q    = lane >> 3;                // k-chunk 0..7
    const int rr   = lane & 7;                 // row-in-wave 0..7
    const int g    = wave >> 1;                // gate 0..3 (i,f,g,o)
    const int usub = (wave & 1) * 8;
    const int uu   = usub + rr;                // unit-in-WG 0..15 (this row)
    const int unit = w * 16 + uu;              // global unit [0,512)
    const int grow = g * HID + unit;           // z-row [0,2048)

    // weights -> named registers (64 floats; compiler may cache or reload
    // from L2 — v4 measured this at 7475us, strictly better than v5's
    // scratch-spill variant)
    const float4* wp = (const float4*)(Whh + (size_t)grow * HID + q * 64);
    const float4 w0 = wp[0],  w1 = wp[1],  w2 = wp[2],  w3 = wp[3];
    const float4 w4 = wp[4],  w5 = wp[5],  w6 = wp[6],  w7 = wp[7];
    const float4 w8 = wp[8],  w9 = wp[9],  wA = wp[10], wB = wp[11];
    const float4 wC = wp[12], wD = wp[13], wE = wp[14], wF = wp[15];

    // cell state on the first 16 threads (one per unit)
    float c = 0.0f;
    if (tid < 16) c = c0[(size_t)(h0base + dir) * HID + w * 16 + tid];

    // padded h: chunk k lives at [k*68, k*68+64); conflict-free broadcast
    __shared__ __align__(16) float hsp[8 * 68];
    __shared__ float zb[4][16];

    // initial h into padded LDS
    hsp[(tid >> 6) * 68 + (tid & 63)] = h0[(size_t)(h0base + dir) * HID + tid];
    __syncthreads();

    // zP for step 0; thereafter software-pipelined one step ahead (q==0 lanes)
    float zPc = 0.0f;
    if (q == 0) zPc = P[(size_t)(dir ? (SEQ - 1) : 0) * G4H + grow];

    for (int s = 0; s < SEQ; ++s) {
        // prefetch NEXT step's input-projection term (off critical path)
        float zPn = 0.0f;
        if (q == 0 && s + 1 < SEQ) {
            const int tn = dir ? (SEQ - 2 - s) : (s + 1);
            zPn = P[(size_t)tn * G4H + grow];
        }

        // matvec partial: this lane's ordered 64-fma chain, k in [64q,64q+64)
        float acc = 0.0f;
        {
            const float* hb4 = &hsp[q * 68];
            float4 h4;
            h4 = *(const float4*)&hb4[ 0]; acc = fmaf(w0.x,h4.x,acc); acc = fmaf(w0.y,h4.y,acc); acc = fmaf(w0.z,h4.z,acc); acc = fmaf(w0.w,h4.w,acc);
            h4 = *(const float4*)&hb4[ 4]; acc = fmaf(w1.x,h4.x,acc); acc = fmaf(w1.y,h4.y,acc); acc = fmaf(w1.z,h4.z,acc); acc = fmaf(w1.w,h4.w,acc);
            h4 = *(const float4*)&hb4[ 8]; acc = fmaf(w2.x,h4.x,acc); acc = fmaf(w2.y,h4.y,acc); acc = fmaf(w2.z,h4.z,acc); acc = fmaf(w2.w,h4.w,acc);
            h4 = *(const float4*)&hb4[12]; acc = fmaf(w3.x,h4.x,acc); acc = fmaf(w3.y,h4.y,acc); acc = fmaf(w3.z,h4.z,acc); acc = fmaf(w3.w,h4.w,acc);
            h4 = *(const float4*)&hb4[16]; acc = fmaf(w4.x,h4.x,acc); acc = fmaf(w4.y,h4.y,acc); acc = fmaf(w4.z,h4.z,acc); acc = fmaf(w4.w,h4.w,acc);
            h4 = *(const float4*)&hb4[20]; acc = fmaf(w5.x,h4.x,acc); acc = fmaf(w5.y,h4.y,acc); acc = fmaf(w5.z,h4.z,acc); acc = fmaf(w5.w,h4.w,acc);
            h4 = *(const float4*)&hb4[24]; acc = fmaf(w6.x,h4.x,acc); acc = fmaf(w6.y,h4.y,acc); acc = fmaf(w6.z,h4.z,acc); acc = fmaf(w6.w,h4.w,acc);
            h4 = *(const float4*)&hb4[28]; acc = fmaf(w7.x,h4.x,acc); acc = fmaf(w7.y,h4.y,acc); acc = fmaf(w7.z,h4.z,acc); acc = fmaf(w7.w,h4.w,acc);
            h4 = *(const float4*)&hb4[32]; acc = fmaf(w8.x,h4.x,acc); acc = fmaf(w8.y,h4.y,acc); acc = fmaf(w8.z,h4.z,acc); acc = fmaf(w8.w,h4.w,acc);
            h4 = *(const float4*)&hb4[36]; acc = fmaf(w9.x,h4.x,acc); acc = fmaf(w9.y,h4.y,acc); acc = fmaf(w9.z,h4.z,acc); acc = fmaf(w9.w,h4.w,acc);
            h4 = *(const float4*)&hb4[40]; acc = fmaf(wA.x,h4.x,acc); acc = fmaf(wA.y,h4.y,acc); acc = fmaf(wA.z,h4.z,acc); acc = fmaf(wA.w,h4.w,acc);
            h4 = *(const float4*)&hb4[44]; acc = fmaf(wB.x,h4.x,acc); acc = fmaf(wB.y,h4.y,acc); acc = fmaf(wB.z,h4.z,acc); acc = fmaf(wB.w,h4.w,acc);
            h4 = *(const float4*)&hb4[48]; acc = fmaf(wC.x,h4.x,acc); acc = fmaf(wC.y,h4.y,acc); acc = fmaf(wC.z,h4.z,acc); acc = fmaf(wC.w,h4.w,acc);
            h4 = *(const float4*)&hb4[52]; acc = fmaf(wD.x,h4.x,acc); acc = fmaf(wD.y,h4.y,acc); acc = fmaf(wD.z,h4.z,acc); acc = fmaf(wD.w,h4.w,acc);
            h4 = *(const float4*)&hb4[56]; acc = fmaf(wE.x,h4.x,acc); acc = fmaf(wE.y,h4.y,acc); acc = fmaf(wE.z,h4.z,acc); acc = fmaf(wE.w,h4.w,acc);
            h4 = *(const float4*)&hb4[60]; acc = fmaf(wF.x,h4.x,acc); acc = fmaf(wF.y,h4.y,acc); acc = fmaf(wF.z,h4.z,acc); acc = fmaf(wF.w,h4.w,acc);
        }

        // s2_i = c_{2i} + c_{2i+1}: even-q lanes hold own(even) + partner(odd)
        const float s2 = acc + __shfl_xor(acc, 8);
        // z = ((s2_0 + s2_1) + s2_2) + s2_3 + zP   (exact v1 association)
        float z = __shfl(s2, rr) + __shfl(s2, 16 + rr);
        z += __shfl(s2, 32 + rr);
        z += __shfl(s2, 48 + rr);
        z += __shfl(zPc, rr);                      // zP lives on q==0 lane rr of this wave

        // PRE-BARRIER activation (wave-uniform branch; identical function on
        // identical input as v4's post-barrier version -> bit-exact)
        const float act = (g == 2) ? tanhf(z) : sigm(z);

        // write this row's activated gate once (q==0 lanes)
        if (q == 0) zb[g][uu] = act;
        __syncthreads();                           // B1: zb ready, hsp reads done

        if (tid < 16) {
            const float ai = zb[0][tid];
            const float af = zb[1][tid];
            const float ag = zb[2][tid];
            const float ao = zb[3][tid];
            const float cn = af * c + ai * ag;     // == sigm(zf)*c + sigm(zi)*tanhf(zg)
            const float hv = ao * tanhf(cn);       // == sigm(zo)*tanhf(cn)
            c = cn;
            // 16 lanes x 4B contiguous, 64B-aligned = one write transaction
            __hip_atomic_store(&histW[(size_t)(s + 1) * HID + w * 16 + tid], hv,
                               __ATOMIC_RELAXED, __HIP_MEMORY_SCOPE_AGENT);
        }
        zPc = zPn;

        if (s + 1 < SEQ) {
            // 2-deep pipelined poll, v4 distribution (all 512 threads x 1 word).
            // Values are write-once: first non-sentinel observation is final.
            const uint32_t* src = (const uint32_t*)(histW + (size_t)(s + 1) * HID);
            uint32_t A = __hip_atomic_load(&src[tid], __ATOMIC_RELAXED, __HIP_MEMORY_SCOPE_AGENT);
            uint32_t B = __hip_atomic_load(&src[tid], __ATOMIC_RELAXED, __HIP_MEMORY_SCOPE_AGENT);
            while (A == 0xFFFFFFFFu) {
                A = B;
                B = __hip_atomic_load(&src[tid], __ATOMIC_RELAXED, __HIP_MEMORY_SCOPE_AGENT);
            }
            hsp[(tid >> 6) * 68 + (tid & 63)] = __uint_as_float(A);
            __syncthreads();                       // B2: hs[s+1] complete
        }
    }
}

// =====================================================================
// feats[t][j] = b_tag[j] + sum_k y1[t][k] * Wtag[j][k], y1 from hist buffers.
// One wave per t-row.
// =====================================================================
__global__ __launch_bounds__(256) void feats_kernel(
    const float* __restrict__ hf, const float* __restrict__ hb,
    const float* __restrict__ Wtag, const float* __restrict__ btag, float* __restrict__ feats)
{
    const int wv = threadIdx.x >> 6, lane = threadIdx.x & 63;
    const int t  = blockIdx.x * 4 + wv;
    const int k0 = lane * 16;
    const float* src = (k0 < 512) ? (hf + (size_t)(t + 1) * HID + k0)
                                  : (hb + (size_t)(SEQ - t) * HID + (k0 - 512));
    const float4 y0 = ((const float4*)src)[0];
    const float4 y1 = ((const float4*)src)[1];
    const float4 y2 = ((const float4*)src)[2];
    const float4 y3 = ((const float4*)src)[3];
    for (int j = 0; j < KTAG; ++j) {
        const float4* wp = (const float4*)&Wtag[(size_t)j * 1024 + k0];
        const float4 w0 = wp[0], w1 = wp[1], w2 = wp[2], w3 = wp[3];
        float p = 0.0f;
        p = fmaf(y0.x, w0.x, p); p = fmaf(y0.y, w0.y, p); p = fmaf(y0.z, w0.z, p); p = fmaf(y0.w, w0.w, p);
        p = fmaf(y1.x, w1.x, p); p = fmaf(y1.y, w1.y, p); p = fmaf(y1.z, w1.z, p); p = fmaf(y1.w, w1.w, p);
        p = fmaf(y2.x, w2.x, p); p = fmaf(y2.y, w2.y, p); p = fmaf(y2.z, w2.z, p); p = fmaf(y2.w, w2.w, p);
        p = fmaf(y3.x, w3.x, p); p = fmaf(y3.y, w3.y, p); p = fmaf(y3.z, w3.z, p); p = fmaf(y3.w, w3.w, p);
        #pragma unroll
        for (int off = 32; off; off >>= 1) p += __shfl_xor(p, off);
        if (lane == 0) feats[(size_t)t * KTAG + j] = p + btag[j];
    }
}

// =====================================================================
// Sequential Viterbi max scan (bit-exact vs reference, no argmax on chain).
// 1 wave. Lane layout: to = lane%24, half = lane/24 covers 12 'from' each.
// fv rows stored to fvstore (slot 0 = init, slot t+1 = fv_t) for bp recompute.
// =====================================================================
__global__ __launch_bounds__(64) void viterbi_scan(
    const float* __restrict__ feats, const float* __restrict__ trans,
    float* __restrict__ fvstore, float* __restrict__ out, int* __restrict__ bestb)
{
    const int lane = threadIdx.x;
    const int to = lane % 24, hh = lane / 24;
    const bool act = hh < 2;
    const int hb = (hh & 1) * 12;

    float tr[12], fvr[12];
    #pragma unroll
    for (int i = 0; i < 12; ++i) tr[i] = act ? trans[to * 24 + hb + i] : -3.0e37f;
    #pragma unroll
    for (int i = 0; i < 12; ++i) fvr[i] = (hb + i == 0) ? 0.0f : NEGV;
    if (lane < 24) fvstore[lane] = (lane == 0) ? 0.0f : NEGV;

    float ftc = (lane < 24) ? feats[lane] : 0.0f;
    const int partner = act ? (to + ((hh ^ 1) * 24)) : lane;
    float fvnew = 0.0f;

    for (int t = 0; t < SEQ; ++t) {
        const float ftn = (lane < 24 && t + 1 < SEQ) ? feats[(size_t)(t + 1) * KTAG + lane] : 0.0f;
        float v0  = fvr[0]  + tr[0],  v1  = fvr[1]  + tr[1];
        float v2  = fvr[2]  + tr[2],  v3  = fvr[3]  + tr[3];
        float v4  = fvr[4]  + tr[4],  v5  = fvr[5]  + tr[5];
        float v6  = fvr[6]  + tr[6],  v7  = fvr[7]  + tr[7];
        float v8  = fvr[8]  + tr[8],  v9  = fvr[9]  + tr[9];
        float v10 = fvr[10] + tr[10], v11 = fvr[11] + tr[11];
        float m = fmaxf(fmaxf(fmaxf(v0, v1), fmaxf(v2, v3)),
                        fmaxf(fmaxf(v4, v5), fmaxf(v6, v7)));
        m = fmaxf(m, fmaxf(fmaxf(v8, v9), fmaxf(v10, v11)));
        m = fmaxf(m, __shfl(m, partner));
        fvnew = m + ftc;                 // valid on lanes < 24
        if (lane < 24) fvstore[(size_t)(t + 1) * KTAG + lane] = fvnew;
        #pragma unroll
        for (int i = 0; i < 12; ++i) fvr[i] = __shfl(fvnew, hb + i);   // re-replicate
        ftc = ftn;
    }

    // terminal
    float val = -3.0e38f; int idx = lane;
    if (lane < 24) {
        val = fvnew + trans[1 * 24 + lane];          // transitions[STOP][from]
        if (lane == 0 || lane == 1) val = NEGV;      // exclude START, STOP
    }
    #pragma unroll
    for (int off = 16; off; off >>= 1) {
        const float ov = __shfl_xor(val, off);
        const int   oi = __shfl_xor(idx, off);
        if (ov > val || (ov == val && oi < idx)) { val = ov; idx = oi; }
    }
    if (lane == 0) { out[0] = val; *bestb = idx; }
}

// =====================================================================
// Recompute backpointers in parallel: bp[t][to] = argmax_from(fv_{t-1}[from]+trans)
// Identical fp32 adds + first-index tie rule -> matches the sequential scan.
// =====================================================================
__global__ __launch_bounds__(256) void bp_kernel(
    const float* __restrict__ fvstore, const float* __restrict__ trans, uint8_t* __restrict__ bp)
{
    const int idx = blockIdx.x * 256 + threadIdx.x;
    const int t = idx / KTAG, to = idx % KTAG;
    const float* fv = fvstore + (size_t)t * KTAG;   // slot t = fv_{t-1}
    const float* tr = trans + to * 24;
    float m = fv[0] + tr[0]; int bi = 0;
    #pragma unroll
    for (int f = 1; f < 24; ++f) {
        const float v = fv[f] + tr[f];
        if (v > m) { m = v; bi = f; }
    }
    bp[idx] = (uint8_t)bi;
}

// =====================================================================
// Parallel backtrace via exact integer map composition over 64-step chunks.
// =====================================================================
__global__ __launch_bounds__(1024) void backtrace_kernel(
    const uint8_t* __restrict__ bp, const int* __restrict__ bestb, float* __restrict__ out)
{
    __shared__ uint8_t E[64][24];
    __shared__ uint8_t tops[64];
    const int tid = threadIdx.x;
    const int wv = tid >> 6, lane = tid & 63;

    // phase 1: chunk maps E_c: top_c -> top_{c-1} (applies bp[64c+63] .. bp[64c])
    for (int ci = 0; ci < 4; ++ci) {
        const int ck = wv * 4 + ci;
        if (lane < 24) {
            int y = lane;
            for (int k = 63; k >= 0; --k) y = bp[(size_t)(ck * 64 + k) * KTAG + y];
            E[ck][lane] = (uint8_t)y;
        }
    }
    __syncthreads();

    // phase 2: serial fold over 64 chunk maps
    if (tid == 0) {
        int topc = *bestb;
        tops[63] = (uint8_t)topc;
        for (int ck = 63; ck >= 1; --ck) { topc = E[ck][topc]; tops[ck - 1] = (uint8_t)topc; }
    }
    __syncthreads();

    // phase 3: fill each chunk
    for (int ci = 0; ci < 4; ++ci) {
        const int ck = wv * 4 + ci;
        if (lane == 0) {
            int y = tops[ck];
            out[1 + ck * 64 + 63] = (float)y;
            for (int tt = ck * 64 + 62; tt >= ck * 64; --tt) {
                y = bp[(size_t)(tt + 1) * KTAG + y];
                out[1 + tt] = (float)y;
            }
        }
    }
}

// =====================================================================
extern "C" void kernel_launch(void* const* d_in, const int* in_sizes, int n_in,
                              void* d_out, int out_size, void* d_ws, size_t ws_size,
                              hipStream_t stream)
{
    (void)in_sizes; (void)n_in; (void)out_size; (void)ws_size;
    // Inputs in setup_inputs() dict INSERTION order: transitions is added
    // LAST (after h0/c0), even though the reference signature lists it earlier.
    const float* X     = (const float*)d_in[0];
    const float* Wih0f = (const float*)d_in[1];
    const float* Whh0f = (const float*)d_in[2];
    const float* b0f   = (const float*)d_in[3];
    const float* Wih0b = (const float*)d_in[4];
    const float* Whh0b = (const float*)d_in[5];
    const float* b0b   = (const float*)d_in[6];
    const float* Wih1f = (const float*)d_in[7];
    const float* Whh1f = (const float*)d_in[8];
    const float* b1f   = (const float*)d_in[9];
    const float* Wih1b = (const float*)d_in[10];
    const float* Whh1b = (const float*)d_in[11];
    const float* b1b   = (const float*)d_in[12];
    const float* Wtag  = (const float*)d_in[13];
    const float* btag  = (const float*)d_in[14];
    const float* h0    = (const float*)d_in[15];
    const float* c0    = (const float*)d_in[16];
    const float* trans = (const float*)d_in[17];
    float* out = (float*)d_out;

    // workspace carve-up (floats)
    float* f   = (float*)d_ws;
    float* Pf  = f;                                   // SEQ*2048
    float* Pb  = Pf  + (size_t)SEQ * G4H;             // SEQ*2048
    float* hf0 = Pb  + (size_t)SEQ * G4H;             // (SEQ+1)*512 each
    float* hb0 = hf0 + (size_t)(SEQ + 1) * HID;
    float* hf1 = hb0 + (size_t)(SEQ + 1) * HID;
    float* hb1 = hf1 + (size_t)(SEQ + 1) * HID;
    float* feats = hb1 + (size_t)(SEQ + 1) * HID;     // SEQ*24
    float* fvst  = feats + (size_t)SEQ * KTAG;        // (SEQ+1)*24
    int*   bestb = (int*)(fvst + (size_t)(SEQ + 1) * KTAG);
    uint8_t* bp  = (uint8_t*)(bestb + 4);             // SEQ*24 bytes

    // NaN-sentinel fill for all 4 hist buffers (sync mechanism for the LSTM)
    hipMemsetAsync(hf0, 0xFF, (size_t)4 * (SEQ + 1) * HID * sizeof(float), stream);

    // layer 0: input projection, then persistent bidirectional recurrence
    gemm_proj<<<dim3(SEQ / 128, G4H / 128, 2), 256, 0, stream>>>(
        X, nullptr, nullptr, DIN, 0, Wih0f, b0f, Pf, Wih0b, b0b, Pb);
    lstm_layer<<<64, 512, 0, stream>>>(Pf, Pb, Whh0f, Whh0b, h0, c0, 0, hf0, hb0);

    // layer 1 (P buffers reused; layer-0 input y0 read straight from hist)
    gemm_proj<<<dim3(SEQ / 128, G4H / 128, 2), 256, 0, stream>>>(
        nullptr, hf0, hb0, 1024, 1, Wih1f, b1f, Pf, Wih1b, b1b, Pb);
    lstm_layer<<<64, 512, 0, stream>>>(Pf, Pb, Whh1f, Whh1b, h0, c0, 2, hf1, hb1);

    // tag head + Viterbi
    feats_kernel<<<SEQ / 4, 256, 0, stream>>>(hf1, hb1, Wtag, btag, feats);
    viterbi_scan<<<1, 64, 0, stream>>>(feats, trans, fvst, out, bestb);
    bp_kernel<<<(SEQ * KTAG) / 256, 256, 0, stream>>>(fvst, trans, bp);
    backtrace_kernel<<<1, 1024, 0, stream>>>(bp, bestb, out);
}